// Round 13
// baseline (472.581 us; speedup 1.0000x reference)
//
#include <hip/hip_runtime.h>

#define HH 128
#define WW 128
#define CIN 64
#define COUT 64
#define NTAP 9

typedef __attribute__((ext_vector_type(8))) short bf16x8;   // 8 bf16 (4 VGPRs)
typedef __attribute__((ext_vector_type(4))) float f32x4;    // MFMA accumulator
typedef __attribute__((ext_vector_type(4))) uint  u32x4;
typedef __attribute__((ext_vector_type(2))) float f32x2;

#define XB_ROW_US (130 * 64)                    // ushorts per (sample,row) = 16640 B
#define XB_BYTES  ((size_t)8 * 130 * XB_ROW_US * 2)  // 17,305,600 B
#define XB_OFF    81920

__device__ inline ushort f2bf(float f) {
    union { float f; uint u; } v; v.f = f;
    uint u = v.u;
    return (ushort)((u + 0x7FFF + ((u >> 16) & 1)) >> 16);   // RNE
}

__device__ inline void gl_lds16(const void* g, void* l) {
    __builtin_amdgcn_global_load_lds(
        (const __attribute__((address_space(1))) unsigned int*)g,
        (__attribute__((address_space(3))) unsigned int*)l, 16, 0, 0);
}

// ---------------------------------------------------------------------------
// Launch A (round-11 config, REP-instrumented): prep (1184) + k2 (8192),
// term-major k2 mapping (round-11 validated; round-12 pinning reverted).
// ---------------------------------------------------------------------------
constexpr int K2_NCO = 16;

template <int REP>
__global__ __launch_bounds__(256) void prep_and_terms(
    const float* __restrict__ x, const float* __restrict__ weight,
    const int* __restrict__ term_errors, const int* __restrict__ term_feats,
    ushort* __restrict__ xb, ushort* __restrict__ wfrag,
    float* __restrict__ out, int i_first)
{
    __shared__ __align__(16) char smem[130 * 33 * 4];   // 17160 B
    const int bid = blockIdx.x;
    const int t = threadIdx.x;

#pragma unroll 1
    for (int rep = 0; rep < REP; ++rep) {
        asm volatile("" :: "s"(rep) : "memory");   // defeat cross-rep CSE/hoist

        if (bid < 1040) {
            // ---------------- prep_x ----------------
            uint* tile = (uint*)smem;        // [xs][cp], stride 33 dwords
            const int i = bid & 7;           // sample -> XCD = bid%8 = i
            const int r = bid >> 3;          // xb row; image row = r-1
            uint* dst = (uint*)(xb + (size_t)(i * 130 + r) * XB_ROW_US);
            const int ir = r - 1;
            if (ir < 0 || ir >= HH) {
                u32x4* d4 = (u32x4*)dst;
                for (int e = t; e < 1040; e += 256) d4[e] = (u32x4){0, 0, 0, 0};
            } else {
                const float* xrow = x + ((size_t)i * CIN * HH + ir) * WW;
                if (t < 64) tile[((t >> 5) ? 129 : 0) * 33 + (t & 31)] = 0;
#pragma unroll
                for (int k = 0; k < 8; ++k) {
                    int idx = k * 256 + t;
                    int cp  = idx >> 6;          // 0..31
                    int xs2 = idx & 63;          // xs = 1+2*xs2, 2+2*xs2
                    const float* p = xrow + (size_t)(2 * cp) * HH * WW + 2 * xs2;
                    f32x2 lo = *(const f32x2*)p;
                    f32x2 hi = *(const f32x2*)(p + HH * WW);
                    tile[(1 + 2 * xs2) * 33 + cp] = (uint)f2bf(lo[0]) | ((uint)f2bf(hi[0]) << 16);
                    tile[(2 + 2 * xs2) * 33 + cp] = (uint)f2bf(lo[1]) | ((uint)f2bf(hi[1]) << 16);
                }
                __syncthreads();
                for (int e = t; e < 1040; e += 256) {
                    int xs = e >> 3, c = e & 7;
                    int slot = c ^ (xs & 7);
                    int s = xs * 33 + c * 4;
                    u32x4 w = {tile[s], tile[s + 1], tile[s + 2], tile[s + 3]};
                    *(u32x4*)(dst + xs * 32 + slot * 4) = w;
                }
                __syncthreads();   // tile safe for next rep
            }
        } else if (bid < 1184) {
            // ---------------- prep_w ----------------
            int idx = (bid - 1040) * 256 + t;     // 144 blocks -> 36864
            if (idx < NTAP * 2 * 4 * 64 * 8) {
                int j  = idx & 7;
                int l  = (idx >> 3) & 63;
                int ks = (idx >> 9) & 1;
                int rem = idx >> 10;              // f*9 + tap
                int tp = rem % NTAP;
                int f  = rem / NTAP;
                int co = f * 16 + (l & 15);
                int ci = ks * 32 + (l >> 4) * 8 + j;
                wfrag[idx] = f2bf(weight[((size_t)co * CIN + ci) * NTAP + tp]);
            }
        } else {
            // ---------------- k2: per-term conv, nt stores, term-major ----
            float (*tile)[132] = (float(*)[132])smem;
            const int k2id  = bid - 1184;         // 0..8191, term-major
            const int tt    = k2id >> 6;
            const int sub   = k2id & 63;
            const int strip = sub & 15;
            const int cog   = sub >> 4;
            const int e = term_errors[tt];
            const int f = term_feats[tt];
            const float* xp = x + ((size_t)e * CIN + f) * HH * WW;
            const int y0 = strip * 8;

            for (int idx = t; idx < 10 * 130; idx += 256) {
                int gy = idx / 130, gx = idx - gy * 130;
                int yy = y0 + gy - 1, xx = gx - 1;
                float v = 0.f;
                if (yy >= 0 && yy < HH && xx >= 0 && xx < WW) v = xp[yy * WW + xx];
                tile[gy][gx] = v;
            }
            __syncthreads();

            const int r  = t >> 5;
            const int cq = (t & 31) * 4;
            float xv[3][6];
#pragma unroll
            for (int kh = 0; kh < 3; ++kh)
#pragma unroll
                for (int jj = 0; jj < 6; ++jj)
                    xv[kh][jj] = tile[r + kh][cq + jj];

            const int oy = y0 + r;
#pragma unroll
            for (int c = 0; c < K2_NCO; ++c) {
                int co = cog * K2_NCO + c;
                const float* wc = weight + ((size_t)co * CIN + f) * 9;
                float op[4];
#pragma unroll
                for (int p = 0; p < 4; ++p) {
                    float s = 0.f;
#pragma unroll
                    for (int kh = 0; kh < 3; ++kh)
#pragma unroll
                        for (int kw = 0; kw < 3; ++kw)
                            s = fmaf(xv[kh][p + kw], wc[kh * 3 + kw], s);
                    op[p] = s;
                }
                f32x4 v4 = {op[0], op[1], op[2], op[3]};
                __builtin_nontemporal_store(v4, (f32x4*)&out[
                    ((((size_t)(i_first + tt)) * COUT + co) * HH + oy) * WW + cq]);
            }
            __syncthreads();   // tile safe for next rep
        }
    }
}

// ---------------------------------------------------------------------------
// Launch B: Kernel 1 v4 (round-10/11 validated, nt stores) — PRODUCTION.
// ---------------------------------------------------------------------------
__global__ __launch_bounds__(256, 2) void conv_first_v4(
    const ushort* __restrict__ xb, const ushort* __restrict__ wfrag,
    const float* __restrict__ bias, float* __restrict__ out)
{
    __shared__ __align__(16) ushort A[4 * 130 * 64];   // 66560 B
    const int bid = blockIdx.x;
    const int i  = bid & 7;                // sample -> XCD locality
    const int y0 = (bid >> 3) * 2;         // 0..126
    const int t = threadIdx.x;

    const char* src = (const char*)(xb + (size_t)(i * 130 + y0) * XB_ROW_US);
#pragma unroll
    for (int it = 0; it < 16; ++it)
        gl_lds16(src + it * 4096 + t * 16, (char*)A + it * 4096 + t * 16);
    if (t < 64)
        gl_lds16(src + 65536 + t * 16, (char*)A + 65536 + t * 16);
    __syncthreads();

    const int wv = t >> 6;
    const int rl = wv & 1;                 // row within pair
    const int ch = wv >> 1;                // co half
    const int l  = t & 63;
    const int g  = l >> 4;                 // k-group
    const int ln = l & 15;
    const int y  = y0 + rl;

    f32x4 acc[2][8];                       // [fl][xfi]
#pragma unroll
    for (int fl = 0; fl < 2; ++fl)
#pragma unroll
        for (int xfi = 0; xfi < 8; ++xfi)
            acc[fl][xfi] = (f32x4){0.f, 0.f, 0.f, 0.f};

    const bf16x8* Wp = (const bf16x8*)wfrag;

#pragma unroll
    for (int tap = 0; tap < NTAP; ++tap) {
        const int kh = tap / 3, kw = tap % 3;
        bf16x8 wf[2][2];                   // [ks][fl]
#pragma unroll
        for (int fl = 0; fl < 2; ++fl)
#pragma unroll
            for (int ks = 0; ks < 2; ++ks)
                wf[ks][fl] = Wp[(((ch * 2 + fl) * NTAP + tap) * 2 + ks) * 64 + l];
#pragma unroll
        for (int xfi = 0; xfi < 8; ++xfi) {
            bf16x8 xf[2];
#pragma unroll
            for (int ks = 0; ks < 2; ++ks) {
                int xs = xfi * 16 + ln + kw;           // 0..129
                int slot = (ks * 4 + g) ^ (xs & 7);
                xf[ks] = *(const bf16x8*)(
                    A + (size_t)((rl + kh) * 130 + xs) * 64 + slot * 8);
            }
#pragma unroll
            for (int fl = 0; fl < 2; ++fl)
#pragma unroll
                for (int ks = 0; ks < 2; ++ks)
                    acc[fl][xfi] = __builtin_amdgcn_mfma_f32_16x16x32_bf16(
                        wf[ks][fl], xf[ks], acc[fl][xfi], 0, 0, 0);
        }
    }

#pragma unroll
    for (int fl = 0; fl < 2; ++fl) {
#pragma unroll
        for (int rr = 0; rr < 4; ++rr) {
            int co = ch * 32 + fl * 16 + g * 4 + rr;
            float b = (i == 0) ? bias[co] : 0.f;
#pragma unroll
            for (int xfi = 0; xfi < 8; ++xfi) {
                int xcol = xfi * 16 + ln;
                __builtin_nontemporal_store(acc[fl][xfi][rr] + b,
                    &out[(((size_t)i * COUT + co) * HH + y) * WW + xcol]);
            }
        }
    }
}

// ---------------------------------------------------------------------------
// Fallback path if ws_size too small for xb.
// ---------------------------------------------------------------------------
__global__ void prep_w_fb(const float* __restrict__ weight, ushort* __restrict__ wfrag) {
    int idx = blockIdx.x * 256 + threadIdx.x;
    if (idx >= NTAP * 2 * 4 * 64 * 8) return;
    int j  = idx & 7;
    int l  = (idx >> 3) & 63;
    int ks = (idx >> 9) & 1;
    int rem = idx >> 10;
    int tp = rem % NTAP;
    int f  = rem / NTAP;
    int co = f * 16 + (l & 15);
    int ci = ks * 32 + (l >> 4) * 8 + j;
    wfrag[idx] = f2bf(weight[((size_t)co * CIN + ci) * NTAP + tp]);
}

__global__ __launch_bounds__(256, 3) void conv_first_mfma_fb(
    const float* __restrict__ x, const ushort* __restrict__ wfrag,
    const float* __restrict__ bias, float* __restrict__ out)
{
    __shared__ ushort A[3 * 130 * 64];
    const int wg = (blockIdx.x & 7) * 128 + (blockIdx.x >> 3);
    const int i = wg >> 7;
    const int y = wg & 127;
    const int t = threadIdx.x;
    {
        uint* Az = (uint*)A;
        for (int e = t; e < 6 * 32; e += 256) {
            int rr = e >> 5;
            int kh = rr >> 1;
            int xs = (rr & 1) ? 129 : 0;
            Az[(kh * 130 + xs) * 32 + (e & 31)] = 0;
        }
    }
    const float* xi = x + (size_t)i * CIN * HH * WW;
    for (int it = 0; it < 48; ++it) {
        int flat = it * 256 + t;
        int xs = (flat & 127) + 1;
        int cp = (flat >> 7) & 31;
        int kh = flat >> 12;
        int yy = y + kh - 1;
        uint v = 0;
        if (yy >= 0 && yy < HH) {
            const float* p = xi + ((size_t)(2 * cp) * HH + yy) * WW + (xs - 1);
            v = (uint)f2bf(p[0]) | ((uint)f2bf(p[HH * WW]) << 16);
        }
        int slot = (cp >> 2) ^ (xs & 7);
        ((uint*)A)[(kh * 130 + xs) * 32 + slot * 4 + (cp & 3)] = v;
    }
    __syncthreads();

    const int wv = t >> 6;
    const int l  = t & 63;
    const int g  = l >> 4;
    const int ln = l & 15;
    const int xbase = wv * 32;
    f32x4 acc[4][2];
#pragma unroll
    for (int f = 0; f < 4; ++f)
#pragma unroll
        for (int xfi = 0; xfi < 2; ++xfi)
            acc[f][xfi] = (f32x4){0.f, 0.f, 0.f, 0.f};
    const bf16x8* Wp = (const bf16x8*)wfrag;
#pragma unroll
    for (int tap = 0; tap < NTAP; ++tap) {
        const int kh = tap / 3, kw = tap % 3;
        bf16x8 wf[2][4];
#pragma unroll
        for (int ks = 0; ks < 2; ++ks)
#pragma unroll
            for (int f = 0; f < 4; ++f)
                wf[ks][f] = Wp[((f * NTAP + tap) * 2 + ks) * 64 + l];
        bf16x8 xf_[2][2];
#pragma unroll
        for (int xfi = 0; xfi < 2; ++xfi)
#pragma unroll
            for (int ks = 0; ks < 2; ++ks) {
                int xs = xbase + xfi * 16 + ln + kw;
                int slot = (ks * 4 + g) ^ (xs & 7);
                xf_[xfi][ks] = *(const bf16x8*)(A + (size_t)(kh * 130 + xs) * 64 + slot * 8);
            }
#pragma unroll
        for (int f = 0; f < 4; ++f)
#pragma unroll
            for (int xfi = 0; xfi < 2; ++xfi)
#pragma unroll
                for (int ks = 0; ks < 2; ++ks)
                    acc[f][xfi] = __builtin_amdgcn_mfma_f32_16x16x32_bf16(
                        wf[ks][f], xf_[xfi][ks], acc[f][xfi], 0, 0, 0);
    }
#pragma unroll
    for (int f = 0; f < 4; ++f)
#pragma unroll
        for (int r = 0; r < 4; ++r) {
            int co = f * 16 + g * 4 + r;
            float b = (i == 0) ? bias[co] : 0.f;
#pragma unroll
            for (int xfi = 0; xfi < 2; ++xfi) {
                int xcol = xbase + xfi * 16 + ln;
                out[(((size_t)i * COUT + co) * HH + y) * WW + xcol] = acc[f][xfi][r] + b;
            }
        }
}

__global__ __launch_bounds__(256) void conv_terms_fb(
    const float* __restrict__ x, const float* __restrict__ weight,
    const int* __restrict__ term_errors, const int* __restrict__ term_feats,
    float* __restrict__ out, int i_first)
{
    __shared__ float tile[10][132];
    const int tt    = blockIdx.y;
    const int strip = blockIdx.x & 15;
    const int cog   = blockIdx.x >> 4;
    const int e = term_errors[tt];
    const int f = term_feats[tt];
    const float* xp = x + ((size_t)e * CIN + f) * HH * WW;
    const int y0 = strip * 8;
    for (int idx = threadIdx.x; idx < 10 * 130; idx += 256) {
        int gy = idx / 130, gx = idx % 130;
        int yy = y0 + gy - 1, xx = gx - 1;
        float v = 0.f;
        if (yy >= 0 && yy < HH && xx >= 0 && xx < WW) v = xp[yy * WW + xx];
        tile[gy][gx] = v;
    }
    __syncthreads();
    const int r  = threadIdx.x >> 5;
    const int cq = (threadIdx.x & 31) * 4;
    float xv[3][6];
#pragma unroll
    for (int kh = 0; kh < 3; ++kh)
#pragma unroll
        for (int j = 0; j < 6; ++j)
            xv[kh][j] = tile[r + kh][cq + j];
    const int oy = y0 + r;
#pragma unroll
    for (int c = 0; c < K2_NCO; ++c) {
        int co = cog * K2_NCO + c;
        const float* wc = weight + ((size_t)co * CIN + f) * 9;
        float op[4];
#pragma unroll
        for (int p = 0; p < 4; ++p) {
            float s = 0.f;
#pragma unroll
            for (int kh = 0; kh < 3; ++kh)
#pragma unroll
                for (int kw = 0; kw < 3; ++kw)
                    s = fmaf(xv[kh][p + kw], wc[kh * 3 + kw], s);
            op[p] = s;
        }
        float4* dst = (float4*)&out[
            ((((size_t)(i_first + tt)) * COUT + co) * HH + oy) * WW + cq];
        *dst = make_float4(op[0], op[1], op[2], op[3]);
    }
}

extern "C" void kernel_launch(void* const* d_in, const int* in_sizes, int n_in,
                              void* d_out, int out_size, void* d_ws, size_t ws_size,
                              hipStream_t stream) {
    const float* x          = (const float*)d_in[0];
    const float* weight     = (const float*)d_in[1];
    const float* bias       = (const float*)d_in[2];
    const int* term_errors  = (const int*)d_in[3];
    const int* term_feats   = (const int*)d_in[4];
    float* out = (float*)d_out;
    ushort* wfrag = (ushort*)d_ws;

    const int T = in_sizes[3];                      // 128
    const int n_out = out_size / (COUT * HH * WW);  // 136
    const int i_first = n_out - T;                  // 8

    if (ws_size >= XB_OFF + XB_BYTES) {
        ushort* xb = (ushort*)((char*)d_ws + XB_OFF);
        // MEASUREMENT: launch A REP x5 -> surfaces in top-5 with counters.
        prep_and_terms<5><<<1184 + 8192, 256, 0, stream>>>(
            x, weight, term_errors, term_feats, xb, wfrag, out, i_first);
        // Launch B: production k1_v4 (deduce its cost: total - 5*A).
        conv_first_v4<<<512, 256, 0, stream>>>(xb, wfrag, bias, out);
    } else {
        prep_w_fb<<<(NTAP * 2 * 4 * 64 * 8 + 255) / 256, 256, 0, stream>>>(weight, wfrag);
        conv_first_mfma_fb<<<i_first * HH, 256, 0, stream>>>(x, wfrag, bias, out);
        dim3 g2(16 * (COUT / K2_NCO), T);
        conv_terms_fb<<<g2, 256, 0, stream>>>(x, weight, term_errors, term_feats,
                                              out, i_first);
    }
}

// Round 14
// 122.613 us; speedup vs baseline: 3.8542x; 3.8542x over previous
//
#include <hip/hip_runtime.h>

#define HH 128
#define WW 128
#define CIN 64
#define COUT 64
#define NTAP 9

typedef __attribute__((ext_vector_type(8))) short bf16x8;   // 8 bf16 (4 VGPRs)
typedef __attribute__((ext_vector_type(4))) float f32x4;    // MFMA accumulator
typedef __attribute__((ext_vector_type(4))) uint  u32x4;
typedef __attribute__((ext_vector_type(2))) float f32x2;

#define XB_ROW_US (130 * 64)                    // ushorts per (sample,row) = 16640 B
#define XB_BYTES  ((size_t)8 * 130 * XB_ROW_US * 2)  // 17,305,600 B
#define XB_OFF    81920

__device__ inline ushort f2bf(float f) {
    union { float f; uint u; } v; v.f = f;
    uint u = v.u;
    return (ushort)((u + 0x7FFF + ((u >> 16) & 1)) >> 16);   // RNE
}

__device__ inline void gl_lds16(const void* g, void* l) {
    __builtin_amdgcn_global_load_lds(
        (const __attribute__((address_space(1))) unsigned int*)g,
        (__attribute__((address_space(3))) unsigned int*)l, 16, 0, 0);
}

// ---------------------------------------------------------------------------
// wfrag layout (co-half contiguous):
//   frag index (bf16x8 units) = ((f*NTAP + tap)*2 + ks)*64 + l
//   co = f*16 + (l&15); ci = ks*32 + (l>>4)*8 + j
// xb layout (SWIZZLED, validated rounds 2/8/10-13):
//   ushort idx(i, r, xs, ci) = (i*130 + r)*XB_ROW_US + xs*64
//                              + (((ci>>3) ^ (xs&7))*8) + (ci&7)
// ---------------------------------------------------------------------------

// ---------------------------------------------------------------------------
// Launch A: k2 FIRST (bids 0..8191) so the 537 MB nt-write stream saturates
// HBM from t=0; prep_x (8192..9231) and prep_w (9232..9375) ride the k2
// drain window (round-13 PMC: A warm = 93 µs @ 75% peak; single-shot was
// ~112 because prep at the head delayed the write ramp).
// ---------------------------------------------------------------------------
constexpr int K2_NCO = 16;

__global__ __launch_bounds__(256) void terms_then_prep(
    const float* __restrict__ x, const float* __restrict__ weight,
    const int* __restrict__ term_errors, const int* __restrict__ term_feats,
    ushort* __restrict__ xb, ushort* __restrict__ wfrag,
    float* __restrict__ out, int i_first)
{
    __shared__ __align__(16) char smem[130 * 33 * 4];   // 17160 B
    const int bid = blockIdx.x;
    const int t = threadIdx.x;

    if (bid < 8192) {
        // ---------------- k2: per-term conv, nt stores, term-major --------
        float (*tile)[132] = (float(*)[132])smem;
        const int k2id  = bid;
        const int tt    = k2id >> 6;
        const int sub   = k2id & 63;
        const int strip = sub & 15;
        const int cog   = sub >> 4;
        const int e = term_errors[tt];
        const int f = term_feats[tt];
        const float* xp = x + ((size_t)e * CIN + f) * HH * WW;
        const int y0 = strip * 8;

        for (int idx = t; idx < 10 * 130; idx += 256) {
            int gy = idx / 130, gx = idx - gy * 130;
            int yy = y0 + gy - 1, xx = gx - 1;
            float v = 0.f;
            if (yy >= 0 && yy < HH && xx >= 0 && xx < WW) v = xp[yy * WW + xx];
            tile[gy][gx] = v;
        }
        __syncthreads();

        const int r  = t >> 5;
        const int cq = (t & 31) * 4;
        float xv[3][6];
#pragma unroll
        for (int kh = 0; kh < 3; ++kh)
#pragma unroll
            for (int jj = 0; jj < 6; ++jj)
                xv[kh][jj] = tile[r + kh][cq + jj];

        const int oy = y0 + r;
#pragma unroll
        for (int c = 0; c < K2_NCO; ++c) {
            int co = cog * K2_NCO + c;
            const float* wc = weight + ((size_t)co * CIN + f) * 9;
            float op[4];
#pragma unroll
            for (int p = 0; p < 4; ++p) {
                float s = 0.f;
#pragma unroll
                for (int kh = 0; kh < 3; ++kh)
#pragma unroll
                    for (int kw = 0; kw < 3; ++kw)
                        s = fmaf(xv[kh][p + kw], wc[kh * 3 + kw], s);
                op[p] = s;
            }
            f32x4 v4 = {op[0], op[1], op[2], op[3]};
            __builtin_nontemporal_store(v4, (f32x4*)&out[
                ((((size_t)(i_first + tt)) * COUT + co) * HH + oy) * WW + cq]);
        }
    } else if (bid < 8192 + 1040) {
        // ---------------- prep_x (tail; rides the k2 drain) ---------------
        uint* tile = (uint*)smem;        // [xs][cp], stride 33 dwords
        const int pid = bid - 8192;
        const int i = pid & 7;           // sample (8192%8==0 -> i = bid&7)
        const int r = pid >> 3;          // xb row; image row = r-1
        uint* dst = (uint*)(xb + (size_t)(i * 130 + r) * XB_ROW_US);  // 4160 uints
        const int ir = r - 1;
        if (ir < 0 || ir >= HH) {
            u32x4* d4 = (u32x4*)dst;
            for (int e = t; e < 1040; e += 256) d4[e] = (u32x4){0, 0, 0, 0};
            return;
        }
        const float* xrow = x + ((size_t)i * CIN * HH + ir) * WW;
        if (t < 64) tile[((t >> 5) ? 129 : 0) * 33 + (t & 31)] = 0;
#pragma unroll
        for (int k = 0; k < 8; ++k) {
            int idx = k * 256 + t;
            int cp  = idx >> 6;          // 0..31
            int xs2 = idx & 63;          // xs = 1+2*xs2, 2+2*xs2
            const float* p = xrow + (size_t)(2 * cp) * HH * WW + 2 * xs2;
            f32x2 lo = *(const f32x2*)p;
            f32x2 hi = *(const f32x2*)(p + HH * WW);
            tile[(1 + 2 * xs2) * 33 + cp] = (uint)f2bf(lo[0]) | ((uint)f2bf(hi[0]) << 16);
            tile[(2 + 2 * xs2) * 33 + cp] = (uint)f2bf(lo[1]) | ((uint)f2bf(hi[1]) << 16);
        }
        __syncthreads();
        for (int e = t; e < 1040; e += 256) {
            int xs = e >> 3, c = e & 7;
            int slot = c ^ (xs & 7);
            int s = xs * 33 + c * 4;
            u32x4 w = {tile[s], tile[s + 1], tile[s + 2], tile[s + 3]};
            *(u32x4*)(dst + xs * 32 + slot * 4) = w;
        }
    } else {
        // ---------------- prep_w (tail) ----------------
        int idx = (bid - 8192 - 1040) * 256 + t;   // 144 blocks -> 36864
        if (idx < NTAP * 2 * 4 * 64 * 8) {
            int j  = idx & 7;
            int l  = (idx >> 3) & 63;
            int ks = (idx >> 9) & 1;
            int rem = idx >> 10;              // f*9 + tap
            int tp = rem % NTAP;
            int f  = rem / NTAP;
            int co = f * 16 + (l & 15);
            int ci = ks * 32 + (l >> 4) * 8 + j;
            wfrag[idx] = f2bf(weight[((size_t)co * CIN + ci) * NTAP + tp]);
        }
    }
}

// ---------------------------------------------------------------------------
// Launch B: Kernel 1 v4 (rounds 10-13 validated, nt stores). ~6 µs measured.
// ---------------------------------------------------------------------------
__global__ __launch_bounds__(256, 2) void conv_first_v4(
    const ushort* __restrict__ xb, const ushort* __restrict__ wfrag,
    const float* __restrict__ bias, float* __restrict__ out)
{
    __shared__ __align__(16) ushort A[4 * 130 * 64];   // 66560 B
    const int bid = blockIdx.x;
    const int i  = bid & 7;                // sample -> XCD locality
    const int y0 = (bid >> 3) * 2;         // 0..126
    const int t = threadIdx.x;

    const char* src = (const char*)(xb + (size_t)(i * 130 + y0) * XB_ROW_US);
#pragma unroll
    for (int it = 0; it < 16; ++it)
        gl_lds16(src + it * 4096 + t * 16, (char*)A + it * 4096 + t * 16);
    if (t < 64)
        gl_lds16(src + 65536 + t * 16, (char*)A + 65536 + t * 16);
    __syncthreads();

    const int wv = t >> 6;
    const int rl = wv & 1;                 // row within pair
    const int ch = wv >> 1;                // co half
    const int l  = t & 63;
    const int g  = l >> 4;                 // k-group
    const int ln = l & 15;
    const int y  = y0 + rl;

    f32x4 acc[2][8];                       // [fl][xfi]
#pragma unroll
    for (int fl = 0; fl < 2; ++fl)
#pragma unroll
        for (int xfi = 0; xfi < 8; ++xfi)
            acc[fl][xfi] = (f32x4){0.f, 0.f, 0.f, 0.f};

    const bf16x8* Wp = (const bf16x8*)wfrag;

#pragma unroll
    for (int tap = 0; tap < NTAP; ++tap) {
        const int kh = tap / 3, kw = tap % 3;
        bf16x8 wf[2][2];                   // [ks][fl]
#pragma unroll
        for (int fl = 0; fl < 2; ++fl)
#pragma unroll
            for (int ks = 0; ks < 2; ++ks)
                wf[ks][fl] = Wp[(((ch * 2 + fl) * NTAP + tap) * 2 + ks) * 64 + l];
#pragma unroll
        for (int xfi = 0; xfi < 8; ++xfi) {
            bf16x8 xf[2];
#pragma unroll
            for (int ks = 0; ks < 2; ++ks) {
                int xs = xfi * 16 + ln + kw;           // 0..129
                int slot = (ks * 4 + g) ^ (xs & 7);
                xf[ks] = *(const bf16x8*)(
                    A + (size_t)((rl + kh) * 130 + xs) * 64 + slot * 8);
            }
#pragma unroll
            for (int fl = 0; fl < 2; ++fl)
#pragma unroll
                for (int ks = 0; ks < 2; ++ks)
                    acc[fl][xfi] = __builtin_amdgcn_mfma_f32_16x16x32_bf16(
                        wf[ks][fl], xf[ks], acc[fl][xfi], 0, 0, 0);
        }
    }

#pragma unroll
    for (int fl = 0; fl < 2; ++fl) {
#pragma unroll
        for (int rr = 0; rr < 4; ++rr) {
            int co = ch * 32 + fl * 16 + g * 4 + rr;
            float b = (i == 0) ? bias[co] : 0.f;
#pragma unroll
            for (int xfi = 0; xfi < 8; ++xfi) {
                int xcol = xfi * 16 + ln;
                __builtin_nontemporal_store(acc[fl][xfi][rr] + b,
                    &out[(((size_t)i * COUT + co) * HH + y) * WW + xcol]);
            }
        }
    }
}

// ---------------------------------------------------------------------------
// Fallback path if ws_size too small for xb.
// ---------------------------------------------------------------------------
__global__ void prep_w_fb(const float* __restrict__ weight, ushort* __restrict__ wfrag) {
    int idx = blockIdx.x * 256 + threadIdx.x;
    if (idx >= NTAP * 2 * 4 * 64 * 8) return;
    int j  = idx & 7;
    int l  = (idx >> 3) & 63;
    int ks = (idx >> 9) & 1;
    int rem = idx >> 10;
    int tp = rem % NTAP;
    int f  = rem / NTAP;
    int co = f * 16 + (l & 15);
    int ci = ks * 32 + (l >> 4) * 8 + j;
    wfrag[idx] = f2bf(weight[((size_t)co * CIN + ci) * NTAP + tp]);
}

__global__ __launch_bounds__(256, 3) void conv_first_mfma_fb(
    const float* __restrict__ x, const ushort* __restrict__ wfrag,
    const float* __restrict__ bias, float* __restrict__ out)
{
    __shared__ ushort A[3 * 130 * 64];
    const int wg = (blockIdx.x & 7) * 128 + (blockIdx.x >> 3);
    const int i = wg >> 7;
    const int y = wg & 127;
    const int t = threadIdx.x;
    {
        uint* Az = (uint*)A;
        for (int e = t; e < 6 * 32; e += 256) {
            int rr = e >> 5;
            int kh = rr >> 1;
            int xs = (rr & 1) ? 129 : 0;
            Az[(kh * 130 + xs) * 32 + (e & 31)] = 0;
        }
    }
    const float* xi = x + (size_t)i * CIN * HH * WW;
    for (int it = 0; it < 48; ++it) {
        int flat = it * 256 + t;
        int xs = (flat & 127) + 1;
        int cp = (flat >> 7) & 31;
        int kh = flat >> 12;
        int yy = y + kh - 1;
        uint v = 0;
        if (yy >= 0 && yy < HH) {
            const float* p = xi + ((size_t)(2 * cp) * HH + yy) * WW + (xs - 1);
            v = (uint)f2bf(p[0]) | ((uint)f2bf(p[HH * WW]) << 16);
        }
        int slot = (cp >> 2) ^ (xs & 7);
        ((uint*)A)[(kh * 130 + xs) * 32 + slot * 4 + (cp & 3)] = v;
    }
    __syncthreads();

    const int wv = t >> 6;
    const int l  = t & 63;
    const int g  = l >> 4;
    const int ln = l & 15;
    const int xbase = wv * 32;
    f32x4 acc[4][2];
#pragma unroll
    for (int f = 0; f < 4; ++f)
#pragma unroll
        for (int xfi = 0; xfi < 2; ++xfi)
            acc[f][xfi] = (f32x4){0.f, 0.f, 0.f, 0.f};
    const bf16x8* Wp = (const bf16x8*)wfrag;
#pragma unroll
    for (int tap = 0; tap < NTAP; ++tap) {
        const int kh = tap / 3, kw = tap % 3;
        bf16x8 wf[2][4];
#pragma unroll
        for (int ks = 0; ks < 2; ++ks)
#pragma unroll
            for (int f = 0; f < 4; ++f)
                wf[ks][f] = Wp[((f * NTAP + tap) * 2 + ks) * 64 + l];
        bf16x8 xf_[2][2];
#pragma unroll
        for (int xfi = 0; xfi < 2; ++xfi)
#pragma unroll
            for (int ks = 0; ks < 2; ++ks) {
                int xs = xbase + xfi * 16 + ln + kw;
                int slot = (ks * 4 + g) ^ (xs & 7);
                xf_[xfi][ks] = *(const bf16x8*)(A + (size_t)(kh * 130 + xs) * 64 + slot * 8);
            }
#pragma unroll
        for (int f = 0; f < 4; ++f)
#pragma unroll
            for (int xfi = 0; xfi < 2; ++xfi)
#pragma unroll
                for (int ks = 0; ks < 2; ++ks)
                    acc[f][xfi] = __builtin_amdgcn_mfma_f32_16x16x32_bf16(
                        wf[ks][f], xf_[xfi][ks], acc[f][xfi], 0, 0, 0);
    }
#pragma unroll
    for (int f = 0; f < 4; ++f)
#pragma unroll
        for (int r = 0; r < 4; ++r) {
            int co = f * 16 + g * 4 + r;
            float b = (i == 0) ? bias[co] : 0.f;
#pragma unroll
            for (int xfi = 0; xfi < 2; ++xfi) {
                int xcol = xbase + xfi * 16 + ln;
                out[(((size_t)i * COUT + co) * HH + y) * WW + xcol] = acc[f][xfi][r] + b;
            }
        }
}

__global__ __launch_bounds__(256) void conv_terms_fb(
    const float* __restrict__ x, const float* __restrict__ weight,
    const int* __restrict__ term_errors, const int* __restrict__ term_feats,
    float* __restrict__ out, int i_first)
{
    __shared__ float tile[10][132];
    const int tt    = blockIdx.y;
    const int strip = blockIdx.x & 15;
    const int cog   = blockIdx.x >> 4;
    const int e = term_errors[tt];
    const int f = term_feats[tt];
    const float* xp = x + ((size_t)e * CIN + f) * HH * WW;
    const int y0 = strip * 8;
    for (int idx = threadIdx.x; idx < 10 * 130; idx += 256) {
        int gy = idx / 130, gx = idx % 130;
        int yy = y0 + gy - 1, xx = gx - 1;
        float v = 0.f;
        if (yy >= 0 && yy < HH && xx >= 0 && xx < WW) v = xp[yy * WW + xx];
        tile[gy][gx] = v;
    }
    __syncthreads();
    const int r  = threadIdx.x >> 5;
    const int cq = (threadIdx.x & 31) * 4;
    float xv[3][6];
#pragma unroll
    for (int kh = 0; kh < 3; ++kh)
#pragma unroll
        for (int j = 0; j < 6; ++j)
            xv[kh][j] = tile[r + kh][cq + j];
    const int oy = y0 + r;
#pragma unroll
    for (int c = 0; c < K2_NCO; ++c) {
        int co = cog * K2_NCO + c;
        const float* wc = weight + ((size_t)co * CIN + f) * 9;
        float op[4];
#pragma unroll
        for (int p = 0; p < 4; ++p) {
            float s = 0.f;
#pragma unroll
            for (int kh = 0; kh < 3; ++kh)
#pragma unroll
                for (int kw = 0; kw < 3; ++kw)
                    s = fmaf(xv[kh][p + kw], wc[kh * 3 + kw], s);
            op[p] = s;
        }
        float4* dst = (float4*)&out[
            ((((size_t)(i_first + tt)) * COUT + co) * HH + oy) * WW + cq];
        *dst = make_float4(op[0], op[1], op[2], op[3]);
    }
}

extern "C" void kernel_launch(void* const* d_in, const int* in_sizes, int n_in,
                              void* d_out, int out_size, void* d_ws, size_t ws_size,
                              hipStream_t stream) {
    const float* x          = (const float*)d_in[0];
    const float* weight     = (const float*)d_in[1];
    const float* bias       = (const float*)d_in[2];
    const int* term_errors  = (const int*)d_in[3];
    const int* term_feats   = (const int*)d_in[4];
    float* out = (float*)d_out;
    ushort* wfrag = (ushort*)d_ws;

    const int T = in_sizes[3];                      // 128
    const int n_out = out_size / (COUT * HH * WW);  // 136
    const int i_first = n_out - T;                  // 8

    if (ws_size >= XB_OFF + XB_BYTES) {
        ushort* xb = (ushort*)((char*)d_ws + XB_OFF);
        // Launch A: k2 first (write stream from t=0), prep rides the drain.
        terms_then_prep<<<8192 + 1040 + 144, 256, 0, stream>>>(
            x, weight, term_errors, term_feats, xb, wfrag, out, i_first);
        // Launch B: dense MFMA conv (~6 µs, reads xb/wfrag from launch A).
        conv_first_v4<<<512, 256, 0, stream>>>(xb, wfrag, bias, out);
    } else {
        prep_w_fb<<<(NTAP * 2 * 4 * 64 * 8 + 255) / 256, 256, 0, stream>>>(weight, wfrag);
        conv_first_mfma_fb<<<i_first * HH, 256, 0, stream>>>(x, wfrag, bias, out);
        dim3 g2(16 * (COUT / K2_NCO), T);
        conv_terms_fb<<<g2, 256, 0, stream>>>(x, weight, term_errors, term_feats,
                                              out, i_first);
    }
}

// Round 15
// 117.311 us; speedup vs baseline: 4.0285x; 1.0452x over previous
//
#include <hip/hip_runtime.h>

#define HH 128
#define WW 128
#define CIN 64
#define COUT 64
#define NTAP 9

typedef __attribute__((ext_vector_type(8))) short bf16x8;   // 8 bf16 (4 VGPRs)
typedef __attribute__((ext_vector_type(4))) float f32x4;    // MFMA accumulator
typedef __attribute__((ext_vector_type(4))) uint  u32x4;
typedef __attribute__((ext_vector_type(2))) float f32x2;

#define XB_ROW_US (130 * 64)                    // ushorts per (sample,row) = 16640 B
#define XB_BYTES  ((size_t)8 * 130 * XB_ROW_US * 2)  // 17,305,600 B
#define XB_OFF    81920

__device__ inline ushort f2bf(float f) {
    union { float f; uint u; } v; v.f = f;
    uint u = v.u;
    return (ushort)((u + 0x7FFF + ((u >> 16) & 1)) >> 16);   // RNE
}

__device__ inline void gl_lds16(const void* g, void* l) {
    __builtin_amdgcn_global_load_lds(
        (const __attribute__((address_space(1))) unsigned int*)g,
        (__attribute__((address_space(3))) unsigned int*)l, 16, 0, 0);
}

// ---------------------------------------------------------------------------
// ROUND-11 BEST CONFIG (117.8 µs), reverted verbatim.
// wfrag layout (co-half contiguous):
//   frag index (bf16x8 units) = ((f*NTAP + tap)*2 + ks)*64 + l
//   co = f*16 + (l&15); ci = ks*32 + (l>>4)*8 + j
// xb layout (SWIZZLED, validated rounds 2/8/10-14):
//   ushort idx(i, r, xs, ci) = (i*130 + r)*XB_ROW_US + xs*64
//                              + (((ci>>3) ^ (xs&7))*8) + (ci&7)
// Measured components (round-13 REP): launch A warm 93.4 µs @ 75% HBM peak,
// single-shot ~112 (cold reads + ramp); k1_v4 ~6 µs. Pinning (r12) and
// tail-prep (r14) both regressed — this ordering is the measured optimum.
// ---------------------------------------------------------------------------
constexpr int K2_NCO = 16;

__global__ __launch_bounds__(256) void prep_and_terms(
    const float* __restrict__ x, const float* __restrict__ weight,
    const int* __restrict__ term_errors, const int* __restrict__ term_feats,
    ushort* __restrict__ xb, ushort* __restrict__ wfrag,
    float* __restrict__ out, int i_first)
{
    __shared__ __align__(16) char smem[130 * 33 * 4];   // 17160 B
    const int bid = blockIdx.x;
    const int t = threadIdx.x;

    if (bid < 1040) {
        // ---------------- prep_x ----------------
        uint* tile = (uint*)smem;        // [xs][cp], stride 33 dwords
        const int i = bid & 7;           // sample -> XCD = bid%8 = i
        const int r = bid >> 3;          // xb row; image row = r-1
        uint* dst = (uint*)(xb + (size_t)(i * 130 + r) * XB_ROW_US);  // 4160 uints
        const int ir = r - 1;
        if (ir < 0 || ir >= HH) {
            u32x4* d4 = (u32x4*)dst;
            for (int e = t; e < 1040; e += 256) d4[e] = (u32x4){0, 0, 0, 0};
            return;
        }
        const float* xrow = x + ((size_t)i * CIN * HH + ir) * WW;
        if (t < 64) tile[((t >> 5) ? 129 : 0) * 33 + (t & 31)] = 0;
#pragma unroll
        for (int k = 0; k < 8; ++k) {
            int idx = k * 256 + t;
            int cp  = idx >> 6;          // 0..31
            int xs2 = idx & 63;          // xs = 1+2*xs2, 2+2*xs2
            const float* p = xrow + (size_t)(2 * cp) * HH * WW + 2 * xs2;
            f32x2 lo = *(const f32x2*)p;
            f32x2 hi = *(const f32x2*)(p + HH * WW);
            tile[(1 + 2 * xs2) * 33 + cp] = (uint)f2bf(lo[0]) | ((uint)f2bf(hi[0]) << 16);
            tile[(2 + 2 * xs2) * 33 + cp] = (uint)f2bf(lo[1]) | ((uint)f2bf(hi[1]) << 16);
        }
        __syncthreads();
        for (int e = t; e < 1040; e += 256) {
            int xs = e >> 3, c = e & 7;
            int slot = c ^ (xs & 7);
            int s = xs * 33 + c * 4;
            u32x4 w = {tile[s], tile[s + 1], tile[s + 2], tile[s + 3]};
            *(u32x4*)(dst + xs * 32 + slot * 4) = w;
        }
    } else if (bid < 1184) {
        // ---------------- prep_w ----------------
        int idx = (bid - 1040) * 256 + t;     // 144 blocks -> 36864
        if (idx < NTAP * 2 * 4 * 64 * 8) {
            int j  = idx & 7;
            int l  = (idx >> 3) & 63;
            int ks = (idx >> 9) & 1;
            int rem = idx >> 10;              // f*9 + tap
            int tp = rem % NTAP;
            int f  = rem / NTAP;
            int co = f * 16 + (l & 15);
            int ci = ks * 32 + (l >> 4) * 8 + j;
            wfrag[idx] = f2bf(weight[((size_t)co * CIN + ci) * NTAP + tp]);
        }
    } else {
        // ---------------- k2: per-term conv, nt stores, term-major --------
        float (*tile)[132] = (float(*)[132])smem;
        const int k2id  = bid - 1184;         // 0..8191, term-major
        const int tt    = k2id >> 6;
        const int sub   = k2id & 63;
        const int strip = sub & 15;
        const int cog   = sub >> 4;
        const int e = term_errors[tt];
        const int f = term_feats[tt];
        const float* xp = x + ((size_t)e * CIN + f) * HH * WW;
        const int y0 = strip * 8;

        for (int idx = t; idx < 10 * 130; idx += 256) {
            int gy = idx / 130, gx = idx - gy * 130;
            int yy = y0 + gy - 1, xx = gx - 1;
            float v = 0.f;
            if (yy >= 0 && yy < HH && xx >= 0 && xx < WW) v = xp[yy * WW + xx];
            tile[gy][gx] = v;
        }
        __syncthreads();

        const int r  = t >> 5;
        const int cq = (t & 31) * 4;
        float xv[3][6];
#pragma unroll
        for (int kh = 0; kh < 3; ++kh)
#pragma unroll
            for (int jj = 0; jj < 6; ++jj)
                xv[kh][jj] = tile[r + kh][cq + jj];

        const int oy = y0 + r;
#pragma unroll
        for (int c = 0; c < K2_NCO; ++c) {
            int co = cog * K2_NCO + c;
            const float* wc = weight + ((size_t)co * CIN + f) * 9;
            float op[4];
#pragma unroll
            for (int p = 0; p < 4; ++p) {
                float s = 0.f;
#pragma unroll
                for (int kh = 0; kh < 3; ++kh)
#pragma unroll
                    for (int kw = 0; kw < 3; ++kw)
                        s = fmaf(xv[kh][p + kw], wc[kh * 3 + kw], s);
                op[p] = s;
            }
            f32x4 v4 = {op[0], op[1], op[2], op[3]};
            __builtin_nontemporal_store(v4, (f32x4*)&out[
                ((((size_t)(i_first + tt)) * COUT + co) * HH + oy) * WW + cq]);
        }
    }
}

// ---------------------------------------------------------------------------
// Launch B: Kernel 1 v4 (rounds 10-13 validated, nt stores). ~6 µs measured.
// ---------------------------------------------------------------------------
__global__ __launch_bounds__(256, 2) void conv_first_v4(
    const ushort* __restrict__ xb, const ushort* __restrict__ wfrag,
    const float* __restrict__ bias, float* __restrict__ out)
{
    __shared__ __align__(16) ushort A[4 * 130 * 64];   // 66560 B
    const int bid = blockIdx.x;
    const int i  = bid & 7;                // sample -> XCD locality
    const int y0 = (bid >> 3) * 2;         // 0..126
    const int t = threadIdx.x;

    const char* src = (const char*)(xb + (size_t)(i * 130 + y0) * XB_ROW_US);
#pragma unroll
    for (int it = 0; it < 16; ++it)
        gl_lds16(src + it * 4096 + t * 16, (char*)A + it * 4096 + t * 16);
    if (t < 64)
        gl_lds16(src + 65536 + t * 16, (char*)A + 65536 + t * 16);
    __syncthreads();

    const int wv = t >> 6;
    const int rl = wv & 1;                 // row within pair
    const int ch = wv >> 1;                // co half
    const int l  = t & 63;
    const int g  = l >> 4;                 // k-group
    const int ln = l & 15;
    const int y  = y0 + rl;

    f32x4 acc[2][8];                       // [fl][xfi]
#pragma unroll
    for (int fl = 0; fl < 2; ++fl)
#pragma unroll
        for (int xfi = 0; xfi < 8; ++xfi)
            acc[fl][xfi] = (f32x4){0.f, 0.f, 0.f, 0.f};

    const bf16x8* Wp = (const bf16x8*)wfrag;

#pragma unroll
    for (int tap = 0; tap < NTAP; ++tap) {
        const int kh = tap / 3, kw = tap % 3;
        bf16x8 wf[2][2];                   // [ks][fl]
#pragma unroll
        for (int fl = 0; fl < 2; ++fl)
#pragma unroll
            for (int ks = 0; ks < 2; ++ks)
                wf[ks][fl] = Wp[(((ch * 2 + fl) * NTAP + tap) * 2 + ks) * 64 + l];
#pragma unroll
        for (int xfi = 0; xfi < 8; ++xfi) {
            bf16x8 xf[2];
#pragma unroll
            for (int ks = 0; ks < 2; ++ks) {
                int xs = xfi * 16 + ln + kw;           // 0..129
                int slot = (ks * 4 + g) ^ (xs & 7);
                xf[ks] = *(const bf16x8*)(
                    A + (size_t)((rl + kh) * 130 + xs) * 64 + slot * 8);
            }
#pragma unroll
            for (int fl = 0; fl < 2; ++fl)
#pragma unroll
                for (int ks = 0; ks < 2; ++ks)
                    acc[fl][xfi] = __builtin_amdgcn_mfma_f32_16x16x32_bf16(
                        wf[ks][fl], xf[ks], acc[fl][xfi], 0, 0, 0);
        }
    }

#pragma unroll
    for (int fl = 0; fl < 2; ++fl) {
#pragma unroll
        for (int rr = 0; rr < 4; ++rr) {
            int co = ch * 32 + fl * 16 + g * 4 + rr;
            float b = (i == 0) ? bias[co] : 0.f;
#pragma unroll
            for (int xfi = 0; xfi < 8; ++xfi) {
                int xcol = xfi * 16 + ln;
                __builtin_nontemporal_store(acc[fl][xfi][rr] + b,
                    &out[(((size_t)i * COUT + co) * HH + y) * WW + xcol]);
            }
        }
    }
}

// ---------------------------------------------------------------------------
// Fallback path if ws_size too small for xb.
// ---------------------------------------------------------------------------
__global__ void prep_w_fb(const float* __restrict__ weight, ushort* __restrict__ wfrag) {
    int idx = blockIdx.x * 256 + threadIdx.x;
    if (idx >= NTAP * 2 * 4 * 64 * 8) return;
    int j  = idx & 7;
    int l  = (idx >> 3) & 63;
    int ks = (idx >> 9) & 1;
    int rem = idx >> 10;
    int tp = rem % NTAP;
    int f  = rem / NTAP;
    int co = f * 16 + (l & 15);
    int ci = ks * 32 + (l >> 4) * 8 + j;
    wfrag[idx] = f2bf(weight[((size_t)co * CIN + ci) * NTAP + tp]);
}

__global__ __launch_bounds__(256, 3) void conv_first_mfma_fb(
    const float* __restrict__ x, const ushort* __restrict__ wfrag,
    const float* __restrict__ bias, float* __restrict__ out)
{
    __shared__ ushort A[3 * 130 * 64];
    const int wg = (blockIdx.x & 7) * 128 + (blockIdx.x >> 3);
    const int i = wg >> 7;
    const int y = wg & 127;
    const int t = threadIdx.x;
    {
        uint* Az = (uint*)A;
        for (int e = t; e < 6 * 32; e += 256) {
            int rr = e >> 5;
            int kh = rr >> 1;
            int xs = (rr & 1) ? 129 : 0;
            Az[(kh * 130 + xs) * 32 + (e & 31)] = 0;
        }
    }
    const float* xi = x + (size_t)i * CIN * HH * WW;
    for (int it = 0; it < 48; ++it) {
        int flat = it * 256 + t;
        int xs = (flat & 127) + 1;
        int cp = (flat >> 7) & 31;
        int kh = flat >> 12;
        int yy = y + kh - 1;
        uint v = 0;
        if (yy >= 0 && yy < HH) {
            const float* p = xi + ((size_t)(2 * cp) * HH + yy) * WW + (xs - 1);
            v = (uint)f2bf(p[0]) | ((uint)f2bf(p[HH * WW]) << 16);
        }
        int slot = (cp >> 2) ^ (xs & 7);
        ((uint*)A)[(kh * 130 + xs) * 32 + slot * 4 + (cp & 3)] = v;
    }
    __syncthreads();

    const int wv = t >> 6;
    const int l  = t & 63;
    const int g  = l >> 4;
    const int ln = l & 15;
    const int xbase = wv * 32;
    f32x4 acc[4][2];
#pragma unroll
    for (int f = 0; f < 4; ++f)
#pragma unroll
        for (int xfi = 0; xfi < 2; ++xfi)
            acc[f][xfi] = (f32x4){0.f, 0.f, 0.f, 0.f};
    const bf16x8* Wp = (const bf16x8*)wfrag;
#pragma unroll
    for (int tap = 0; tap < NTAP; ++tap) {
        const int kh = tap / 3, kw = tap % 3;
        bf16x8 wf[2][4];
#pragma unroll
        for (int ks = 0; ks < 2; ++ks)
#pragma unroll
            for (int f = 0; f < 4; ++f)
                wf[ks][f] = Wp[((f * NTAP + tap) * 2 + ks) * 64 + l];
        bf16x8 xf_[2][2];
#pragma unroll
        for (int xfi = 0; xfi < 2; ++xfi)
#pragma unroll
            for (int ks = 0; ks < 2; ++ks) {
                int xs = xbase + xfi * 16 + ln + kw;
                int slot = (ks * 4 + g) ^ (xs & 7);
                xf_[xfi][ks] = *(const bf16x8*)(A + (size_t)(kh * 130 + xs) * 64 + slot * 8);
            }
#pragma unroll
        for (int f = 0; f < 4; ++f)
#pragma unroll
            for (int xfi = 0; xfi < 2; ++xfi)
#pragma unroll
                for (int ks = 0; ks < 2; ++ks)
                    acc[f][xfi] = __builtin_amdgcn_mfma_f32_16x16x32_bf16(
                        wf[ks][f], xf_[xfi][ks], acc[f][xfi], 0, 0, 0);
    }
#pragma unroll
    for (int f = 0; f < 4; ++f)
#pragma unroll
        for (int r = 0; r < 4; ++r) {
            int co = f * 16 + g * 4 + r;
            float b = (i == 0) ? bias[co] : 0.f;
#pragma unroll
            for (int xfi = 0; xfi < 2; ++xfi) {
                int xcol = xbase + xfi * 16 + ln;
                out[(((size_t)i * COUT + co) * HH + y) * WW + xcol] = acc[f][xfi][r] + b;
            }
        }
}

__global__ __launch_bounds__(256) void conv_terms_fb(
    const float* __restrict__ x, const float* __restrict__ weight,
    const int* __restrict__ term_errors, const int* __restrict__ term_feats,
    float* __restrict__ out, int i_first)
{
    __shared__ float tile[10][132];
    const int tt    = blockIdx.y;
    const int strip = blockIdx.x & 15;
    const int cog   = blockIdx.x >> 4;
    const int e = term_errors[tt];
    const int f = term_feats[tt];
    const float* xp = x + ((size_t)e * CIN + f) * HH * WW;
    const int y0 = strip * 8;
    for (int idx = threadIdx.x; idx < 10 * 130; idx += 256) {
        int gy = idx / 130, gx = idx % 130;
        int yy = y0 + gy - 1, xx = gx - 1;
        float v = 0.f;
        if (yy >= 0 && yy < HH && xx >= 0 && xx < WW) v = xp[yy * WW + xx];
        tile[gy][gx] = v;
    }
    __syncthreads();
    const int r  = threadIdx.x >> 5;
    const int cq = (threadIdx.x & 31) * 4;
    float xv[3][6];
#pragma unroll
    for (int kh = 0; kh < 3; ++kh)
#pragma unroll
        for (int j = 0; j < 6; ++j)
            xv[kh][j] = tile[r + kh][cq + j];
    const int oy = y0 + r;
#pragma unroll
    for (int c = 0; c < K2_NCO; ++c) {
        int co = cog * K2_NCO + c;
        const float* wc = weight + ((size_t)co * CIN + f) * 9;
        float op[4];
#pragma unroll
        for (int p = 0; p < 4; ++p) {
            float s = 0.f;
#pragma unroll
            for (int kh = 0; kh < 3; ++kh)
#pragma unroll
                for (int kw = 0; kw < 3; ++kw)
                    s = fmaf(xv[kh][p + kw], wc[kh * 3 + kw], s);
            op[p] = s;
        }
        float4* dst = (float4*)&out[
            ((((size_t)(i_first + tt)) * COUT + co) * HH + oy) * WW + cq];
        *dst = make_float4(op[0], op[1], op[2], op[3]);
    }
}

extern "C" void kernel_launch(void* const* d_in, const int* in_sizes, int n_in,
                              void* d_out, int out_size, void* d_ws, size_t ws_size,
                              hipStream_t stream) {
    const float* x          = (const float*)d_in[0];
    const float* weight     = (const float*)d_in[1];
    const float* bias       = (const float*)d_in[2];
    const int* term_errors  = (const int*)d_in[3];
    const int* term_feats   = (const int*)d_in[4];
    float* out = (float*)d_out;
    ushort* wfrag = (ushort*)d_ws;

    const int T = in_sizes[3];                      // 128
    const int n_out = out_size / (COUT * HH * WW);  // 136
    const int i_first = n_out - T;                  // 8

    if (ws_size >= XB_OFF + XB_BYTES) {
        ushort* xb = (ushort*)((char*)d_ws + XB_OFF);
        // Launch A: prep (1184) + k2 (8192) fused; prep hides under writes.
        prep_and_terms<<<1184 + 8192, 256, 0, stream>>>(
            x, weight, term_errors, term_feats, xb, wfrag, out, i_first);
        // Launch B: dense MFMA conv (~6 µs, reads xb/wfrag from launch A).
        conv_first_v4<<<512, 256, 0, stream>>>(xb, wfrag, bias, out);
    } else {
        prep_w_fb<<<(NTAP * 2 * 4 * 64 * 8 + 255) / 256, 256, 0, stream>>>(weight, wfrag);
        conv_first_mfma_fb<<<i_first * HH, 256, 0, stream>>>(x, wfrag, bias, out);
        dim3 g2(16 * (COUT / K2_NCO), T);
        conv_terms_fb<<<g2, 256, 0, stream>>>(x, weight, term_errors, term_feats,
                                              out, i_first);
    }
}